// Round 17
// baseline (350.014 us; speedup 1.0000x reference)
//
#include <hip/hip_runtime.h>
#include <cstdint>

typedef __bf16 bf16;
typedef __attribute__((ext_vector_type(8))) __bf16 bf16x8;
typedef __attribute__((ext_vector_type(4))) __bf16 bf16x4;
typedef __attribute__((ext_vector_type(4))) float f32x4;

#define NROWS 100000
#define DIM   512
#define NC    400
#define NTILE 521          // ceil(100000/192) tiles of BM=192
#define NGRID 512          // blocks; blocks 0..8 take a second tile

// ---- workspace layout (bytes) ----
#define WS_WP    0u          // packed W bf16: 458752 B
#define WS_SUMU  458752u
#define WS_SUMV  459152u
#define WS_DSC   459552u
#define WS_VTZT  459776u     // [112][128] bf16
#define WS_U     524288u     // [100000][128] bf16
#define WS_PART  66124288u   // 98 x 12544 f32
#define WS_SUMP  71041536u   // [521][200] f32
#define WS_NEED  72291936u

__device__ __forceinline__ void gload_lds16(const void* g, void* l) {
  __builtin_amdgcn_global_load_lds(
      (const __attribute__((address_space(1))) uint32_t*)g,
      (__attribute__((address_space(3))) uint32_t*)l,
      16, 0, 0);
}

// ---- k1: pack W -> [t][g][448 col][8 e] bf16 (28672 B per tile); zero sums ----
__global__ void k1_prep(const float* __restrict__ W, bf16* __restrict__ wp,
                        float* __restrict__ sums) {
  const int idx = blockIdx.x * 256 + threadIdx.x;
  if (idx < 200) sums[idx] = 0.f;
  if (idx >= 16 * 4 * 448 * 8) return;
  const int e = idx & 7;
  int r = idx >> 3;
  const int col = r % 448; r /= 448;
  const int g = r & 3;
  const int t = r >> 2;
  const int k = t * 32 + 4 * g + ((e < 4) ? e : (12 + e));
  wp[idx] = (bf16)((col < NC) ? W[col * DIM + k] : 0.f);
}

// ---- k2: relu(X@Wt+b) + fused per-block VtZ partial.
// BM=192 x BN=448, BK=32, 16 waves (R15 geometry: wave = 48r x 112c, acc[3][7]).
// R16 schedule: 3-buf A AND B -> ONE wait+barrier per step, STAGE(t+2) after
// the barrier, counted vmcnt spans barriers, setprio around MFMA cluster.
// Grid-stride over 512 blocks (521 tiles) kills the integer-round quantization.
__global__ __launch_bounds__(1024) void k2_main(
    const float* __restrict__ X, const bf16* __restrict__ Wp,
    const float* __restrict__ bias, float* __restrict__ out,
    bf16* __restrict__ U, float* __restrict__ part, float* __restrict__ sumP) {
  __shared__ __align__(16) char pool[159744];  // A: 3x24KB @0 ; B: 3x28KB @73728
  char* Abase0 = pool;
  char* Bbase0 = pool + 73728;

  const int tid  = threadIdx.x;
  const int lane = tid & 63;
  const int wave = tid >> 6;        // 0..15
  const int wm = wave >> 2;         // 0..3 : 48-row group
  const int wn = wave & 3;          // 0..3 : 112-col quarter
  const int m  = lane & 15;
  const int g  = lane >> 4;

  // A staging: 24 chunks of 8 rows x 128B. waves 0-7 own 2 chunks, 8-15 own 1.
  const int nba = (wave < 8) ? 2 : 1;
  const int ca0 = (wave < 8) ? wave * 2 : 16 + (wave - 8);
  const size_t swb = (size_t)(((lane & 7) ^ (lane >> 3)) * 16);
  // B staging: 28 chunks of 1024B. waves 0-11 own 2, waves 12-15 own 1.
  const int nbc = (wave < 12) ? 2 : 1;
  const int bc0 = (wave < 12) ? wave * 2 : 24 + (wave - 12);
  const char* wpc = (const char*)Wp;

  for (int tile = blockIdx.x; tile < NTILE; tile += NGRID) {
    const int rb = tile * 192;

    f32x4 acc[3][7];
#pragma unroll
    for (int i = 0; i < 3; ++i)
#pragma unroll
      for (int j = 0; j < 7; ++j) acc[i][j] = (f32x4){0.f, 0.f, 0.f, 0.f};

    int gr0 = rb + ca0 * 8 + (lane >> 3);       if (gr0 > NROWS - 1) gr0 = NROWS - 1;
    int gr1 = rb + (ca0 + 1) * 8 + (lane >> 3); if (gr1 > NROWS - 1) gr1 = NROWS - 1;
    const char* asrc0 = (const char*)X + (size_t)gr0 * 2048 + swb;
    const char* asrc1 = (const char*)X + (size_t)gr1 * 2048 + swb;

#define STAGE(T, BUF)                                                          \
    do {                                                                       \
      char* ad = Abase0 + (BUF) * 24576 + ca0 * 1024 + lane * 16;              \
      gload_lds16(asrc0 + (size_t)(T) * 128, ad);                              \
      if (nba == 2) gload_lds16(asrc1 + (size_t)(T) * 128, ad + 1024);         \
      const char* bsrc = wpc + (size_t)(T) * 28672;                            \
      for (int q = 0; q < nbc; ++q)                                            \
        gload_lds16(bsrc + (bc0 + q) * 1024 + lane * 16,                       \
                    Bbase0 + (BUF) * 28672 + (bc0 + q) * 1024);                \
    } while (0)

    // prologue: tiles 0 and 1 in flight
    STAGE(0, 0);
    STAGE(1, 1);

#pragma unroll
    for (int t = 0; t < 16; ++t) {
      const int cur = t % 3;
      // drain stage(t); leave stage(t+1) in flight (nba+nbc per class); 1 barrier
      if (t < 15) {
        if (wave < 8)       asm volatile("s_waitcnt vmcnt(4)\n\ts_barrier" ::: "memory");
        else if (wave < 12) asm volatile("s_waitcnt vmcnt(3)\n\ts_barrier" ::: "memory");
        else                asm volatile("s_waitcnt vmcnt(2)\n\ts_barrier" ::: "memory");
      } else {
        asm volatile("s_waitcnt vmcnt(0)\n\ts_barrier" ::: "memory");
      }
      // stage t+2 into buf (t+2)%3 — not read until step t+2, no trailing barrier
      if (t + 2 < 16) STAGE(t + 2, (t + 2) % 3);

      // A fragments (swizzled read, f32 -> bf16), 3 m-frags
      const int sw = (m & 7) * 16;
      const char* abuf = Abase0 + cur * 24576;
      bf16x8 af[3];
#pragma unroll
      for (int mf = 0; mf < 3; ++mf) {
        const char* rowp = abuf + (wm * 48 + mf * 16 + m) * 128;
        f32x4 alo = *(const f32x4*)(rowp + ((16 * g) ^ sw));
        f32x4 ahi = *(const f32x4*)(rowp + ((64 + 16 * g) ^ sw));
        af[mf] = (bf16x8){(bf16)alo.x, (bf16)alo.y, (bf16)alo.z, (bf16)alo.w,
                          (bf16)ahi.x, (bf16)ahi.y, (bf16)ahi.z, (bf16)ahi.w};
      }

      const bf16* Bc = (const bf16*)(Bbase0 + cur * 28672);
      __builtin_amdgcn_s_setprio(1);
#pragma unroll
      for (int nf = 0; nf < 7; ++nf) {
        const int n = wn * 112 + nf * 16 + m;
        bf16x8 bfr = *(const bf16x8*)(Bc + (g * 448 + n) * 8);
#pragma unroll
        for (int mf = 0; mf < 3; ++mf)
          acc[mf][nf] = __builtin_amdgcn_mfma_f32_16x16x32_bf16(af[mf], bfr, acc[mf][nf], 0, 0, 0);
      }
      __builtin_amdgcn_s_setprio(0);
    }
#undef STAGE
    __syncthreads();   // all ds_reads done before pool reuse

    // ---- epilogue E1: bias+relu, U/T stores, V/Z -> LDS transposed, col sums ----
    bf16* ldsVZ = (bf16*)pool;               // [224 rows][200 cols] bf16 = 89600 B
    float* sp   = (float*)(pool + 89600);    // [16][112] f32 = 7168 B
    float csum[7];
#pragma unroll
    for (int nf = 0; nf < 7; ++nf) csum[nf] = 0.f;

#pragma unroll
    for (int mf = 0; mf < 3; ++mf) {
#pragma unroll
      for (int nf = 0; nf < 7; ++nf) {
        const int c = wn * 112 + nf * 16 + m;
        const float bv = (c < NC) ? bias[c] : 0.f;
        const int rl0 = wm * 48 + mf * 16 + 4 * g;
        bf16 vz[4];
#pragma unroll
        for (int r = 0; r < 4; ++r) {
          const int row = rb + rl0 + r;
          float v = fmaxf(acc[mf][nf][r] + bv, 0.f);
          const float v2 = (row < NROWS) ? v : 0.f;
          if (row < NROWS) {
            if (c < 100) U[(size_t)row * 128 + c] = (bf16)v;
            if (c >= 300 && c < NC) out[(size_t)row * 200 + 100 + (c - 300)] = v;
          }
          vz[r] = (bf16)v2;
          if (c < 200) csum[nf] += v2;
        }
        if (c >= 100 && c < 300) {
          const int vr = (c < 200) ? (c - 100) : (112 + (c - 200));
          *(bf16x4*)&ldsVZ[(size_t)vr * 200 + rl0] = (bf16x4){vz[0], vz[1], vz[2], vz[3]};
        }
      }
    }
    // zero pad rows: V 100..111, Z 212..223 (24 rows x 200 cols)
    for (int i = tid; i < 4800; i += 1024) {
      const int rr = (i < 2400) ? (100 + i / 200) : (212 + (i - 2400) / 200);
      ldsVZ[(size_t)rr * 200 + (i % 200)] = (bf16)0.f;
    }
#pragma unroll
    for (int nf = 0; nf < 7; ++nf) {
      float s = csum[nf];
      s += __shfl_xor(s, 16, 64);
      s += __shfl_xor(s, 32, 64);
      if (lane < 16) sp[wave * 112 + nf * 16 + lane] = s;
    }
    __syncthreads();

    // ---- epilogue E2: per-tile VtZ partial (112x112, K=192) + atomics ----
    if (wave < 7) {
      f32x4 acc2[7];
#pragma unroll
      for (int j = 0; j < 7; ++j) acc2[j] = (f32x4){0.f, 0.f, 0.f, 0.f};
      const bf16* vA = ldsVZ + (size_t)(wave * 16 + m) * 200;
#pragma unroll
      for (int kc = 0; kc < 6; ++kc) {
        bf16x4 a0 = *(const bf16x4*)(vA + kc * 32 + 4 * g);
        bf16x4 a1 = *(const bf16x4*)(vA + kc * 32 + 16 + 4 * g);
        bf16x8 af_ = {a0[0], a0[1], a0[2], a0[3], a1[0], a1[1], a1[2], a1[3]};
#pragma unroll
        for (int fj = 0; fj < 7; ++fj) {
          const bf16* vB = ldsVZ + (size_t)(112 + fj * 16 + m) * 200 + kc * 32;
          bf16x4 b0 = *(const bf16x4*)(vB + 4 * g);
          bf16x4 b1 = *(const bf16x4*)(vB + 16 + 4 * g);
          bf16x8 bf_ = {b0[0], b0[1], b0[2], b0[3], b1[0], b1[1], b1[2], b1[3]};
          acc2[fj] = __builtin_amdgcn_mfma_f32_16x16x32_bf16(af_, bf_, acc2[fj], 0, 0, 0);
        }
      }
      float* pb = part + (size_t)(tile % 98) * 12544;
#pragma unroll
      for (int fj = 0; fj < 7; ++fj)
#pragma unroll
        for (int r = 0; r < 4; ++r)
          atomicAdd(&pb[(wave * 16 + 4 * g + r) * 112 + fj * 16 + m], acc2[fj][r]);
    }
    if (tid < 200) {
      const int wq = tid / 112, cc = tid % 112;
      sumP[(size_t)tile * 200 + tid] =
          sp[(0 * 4 + wq) * 112 + cc] + sp[(1 * 4 + wq) * 112 + cc] +
          sp[(2 * 4 + wq) * 112 + cc] + sp[(3 * 4 + wq) * 112 + cc];
    }
    __syncthreads();   // E2 reads done before next tile stages into pool
  }
}

// ---- k4a0: reduce per-tile sums -> sumU/sumV ----
__global__ void k4a0_redsum(const float* __restrict__ sumP,
                            float* __restrict__ sumU, float* __restrict__ sumV) {
  __shared__ float red[4];
  const int c = blockIdx.x;          // 0..199
  const int tid = threadIdx.x;       // 256
  float s = 0.f;
  for (int b = tid; b < NTILE; b += 256) s += sumP[(size_t)b * 200 + c];
#pragma unroll
  for (int off = 1; off < 64; off <<= 1) s += __shfl_xor(s, off, 64);
  if ((tid & 63) == 0) red[tid >> 6] = s;
  __syncthreads();
  if (tid == 0) {
    float t = red[0] + red[1] + red[2] + red[3];
    if (c < 100) sumU[c] = t; else sumV[c - 100] = t;
  }
}

// ---- k4a: Dscale ----
__global__ void k4a_norm(const float* __restrict__ sumU, const float* __restrict__ sumV,
                         float* __restrict__ dsc) {
  const int l = threadIdx.x;  // 64
  float v = 0.f;
  if (l < 50) v = sumU[l] * sumV[l] + sumU[l + 50] * sumV[l + 50];
#pragma unroll
  for (int off = 32; off > 0; off >>= 1) v += __shfl_down(v, off, 64);
  if (l == 0) dsc[0] = 1.f / (v * (1.f / (float)NROWS) + 1e-6f);
}

// ---- k4b: reduce 98 f32 partials, scale, store transposed bf16 [j][128] ----
__global__ void k4b_final(const float* __restrict__ part, const float* __restrict__ dsc,
                          bf16* __restrict__ vtzt) {
  const int idx = blockIdx.x * 256 + threadIdx.x;   // 49 blocks
  if (idx < 1792) vtzt[(idx >> 4) * 128 + 112 + (idx & 15)] = (bf16)0.f;
  if (idx >= 12544) return;
  const int i = idx / 112;
  const int j = idx % 112;
  float s = 0.f;
#pragma unroll 7
  for (int bb = 0; bb < 98; ++bb) s += part[(size_t)bb * 12544 + idx];
  vtzt[j * 128 + i] = (bf16)(s * dsc[0]);
}

// ---- k5: res = U @ VtZS -> out[:, 0:100] ----
__global__ __launch_bounds__(256) void k5_res(
    const bf16* __restrict__ U, const bf16* __restrict__ vtzt,
    float* __restrict__ out) {
  const int tid = threadIdx.x;
  const int lane = tid & 63;
  const int wave = tid >> 6;
  const int m = lane & 15, g = lane >> 4;
  const int rb = blockIdx.x * 128 + wave * 32;

  f32x4 acc[2][7];
#pragma unroll
  for (int i = 0; i < 2; ++i)
#pragma unroll
    for (int j = 0; j < 7; ++j) acc[i][j] = (f32x4){0.f, 0.f, 0.f, 0.f};

  int r0 = rb + m;      if (r0 > NROWS - 1) r0 = NROWS - 1;
  int r1 = rb + 16 + m; if (r1 > NROWS - 1) r1 = NROWS - 1;
  const bf16* u0 = U + (size_t)r0 * 128 + 4 * g;
  const bf16* u1 = U + (size_t)r1 * 128 + 4 * g;
  const bf16* vb = vtzt + 4 * g;

#pragma unroll
  for (int ks = 0; ks < 4; ++ks) {
    bf16x4 A00 = *(const bf16x4*)(u0 + ks * 32);
    bf16x4 A01 = *(const bf16x4*)(u0 + ks * 32 + 16);
    bf16x4 A10 = *(const bf16x4*)(u1 + ks * 32);
    bf16x4 A11 = *(const bf16x4*)(u1 + ks * 32 + 16);
    bf16x8 af0 = {A00[0], A00[1], A00[2], A00[3], A01[0], A01[1], A01[2], A01[3]};
    bf16x8 af1 = {A10[0], A10[1], A10[2], A10[3], A11[0], A11[1], A11[2], A11[3]};
#pragma unroll
    for (int nf = 0; nf < 7; ++nf) {
      const int n = nf * 16 + m;
      bf16x4 B0 = *(const bf16x4*)(vb + n * 128 + ks * 32);
      bf16x4 B1 = *(const bf16x4*)(vb + n * 128 + ks * 32 + 16);
      bf16x8 bfr = {B0[0], B0[1], B0[2], B0[3], B1[0], B1[1], B1[2], B1[3]};
      acc[0][nf] = __builtin_amdgcn_mfma_f32_16x16x32_bf16(af0, bfr, acc[0][nf], 0, 0, 0);
      acc[1][nf] = __builtin_amdgcn_mfma_f32_16x16x32_bf16(af1, bfr, acc[1][nf], 0, 0, 0);
    }
  }
#pragma unroll
  for (int mf = 0; mf < 2; ++mf)
#pragma unroll
    for (int nf = 0; nf < 7; ++nf)
#pragma unroll
      for (int r = 0; r < 4; ++r) {
        const int row = rb + mf * 16 + 4 * g + r;
        const int c = nf * 16 + m;
        if (row < NROWS && c < 100)
          out[(size_t)row * 200 + c] = acc[mf][nf][r];
      }
}

extern "C" void kernel_launch(void* const* d_in, const int* in_sizes, int n_in,
                              void* d_out, int out_size, void* d_ws, size_t ws_size,
                              hipStream_t stream) {
  const float* X = (const float*)d_in[0];
  const float* W = (const float*)d_in[1];
  const float* b = (const float*)d_in[2];
  float* out = (float*)d_out;
  char* ws = (char*)d_ws;
  if (ws_size < WS_NEED) return;

  bf16* wp     = (bf16*)(ws + WS_WP);
  float* sumU  = (float*)(ws + WS_SUMU);
  float* sumV  = (float*)(ws + WS_SUMV);
  float* dsc   = (float*)(ws + WS_DSC);
  bf16* vtzt   = (bf16*)(ws + WS_VTZT);
  bf16* U      = (bf16*)(ws + WS_U);
  float* part  = (float*)(ws + WS_PART);
  float* sumP  = (float*)(ws + WS_SUMP);

  k1_prep<<<896, 256, 0, stream>>>(W, wp, sumU);
  hipMemsetAsync(part, 0, 98u * 12544u * 4u, stream);
  k2_main<<<NGRID, 1024, 0, stream>>>(X, wp, b, out, U, part, sumP);
  k4a0_redsum<<<200, 256, 0, stream>>>(sumP, sumU, sumV);
  k4a_norm<<<1, 64, 0, stream>>>(sumU, sumV, dsc);
  k4b_final<<<49, 256, 0, stream>>>(part, dsc, vtzt);
  k5_res<<<782, 256, 0, stream>>>(U, vtzt, out);
}

// Round 18
// 230.145 us; speedup vs baseline: 1.5208x; 1.5208x over previous
//
#include <hip/hip_runtime.h>
#include <cstdint>

typedef __bf16 bf16;
typedef __attribute__((ext_vector_type(8))) __bf16 bf16x8;
typedef __attribute__((ext_vector_type(4))) __bf16 bf16x4;
typedef __attribute__((ext_vector_type(4))) float f32x4;

#define NROWS 100000
#define DIM   512
#define NC    400
#define NTILE 782          // ceil(100000/128)
#define NGRID 768          // blocks 0..13 take a second tile (768+bid)

// ---- workspace layout (bytes) ----
#define WS_WP    0u          // packed W bf16: 458752 B
#define WS_SUMU  458752u
#define WS_SUMV  459152u
#define WS_DSC   459552u
#define WS_VTZT  459776u     // [112][128] bf16
#define WS_U     524288u     // [100000][128] bf16
#define WS_PART  66124288u   // 98 x 12544 f32
#define WS_SUMP  71041536u   // [782][200] f32
#define WS_NEED  71667136u

__device__ __forceinline__ void gload_lds16(const void* g, void* l) {
  __builtin_amdgcn_global_load_lds(
      (const __attribute__((address_space(1))) uint32_t*)g,
      (__attribute__((address_space(3))) uint32_t*)l,
      16, 0, 0);
}

// ---- k1: pack W -> [t][g][448 col][8 e] bf16 (28672 B per tile); zero sums ----
__global__ void k1_prep(const float* __restrict__ W, bf16* __restrict__ wp,
                        float* __restrict__ sums) {
  const int idx = blockIdx.x * 256 + threadIdx.x;
  if (idx < 200) sums[idx] = 0.f;
  if (idx >= 16 * 4 * 448 * 8) return;
  const int e = idx & 7;
  int r = idx >> 3;
  const int col = r % 448; r /= 448;
  const int g = r & 3;
  const int t = r >> 2;
  const int k = t * 32 + 4 * g + ((e < 4) ? e : (12 + e));
  wp[idx] = (bf16)((col < NC) ? W[col * DIM + k] : 0.f);
}

// ---- k2: R16 kernel (512 thr, launch_bounds(512,2), BM=128, 3-buf
// single-barrier schedule, setprio, fused epilogue) + 2-tile loop for the
// 14 tail tiles (NGRID=768) to remove the partial-4th-round quantization.
__global__ __launch_bounds__(512, 2) void k2_main(
    const float* __restrict__ X, const bf16* __restrict__ Wp,
    const float* __restrict__ bias, float* __restrict__ out,
    bf16* __restrict__ U, float* __restrict__ part, float* __restrict__ sumP) {
  __shared__ __align__(16) char pool[135168];  // A: 3x16KB @0 ; B: 3x28KB @49152
  char* Abase0 = pool;
  char* Bbase0 = pool + 49152;

  const int tid  = threadIdx.x;
  const int lane = tid & 63;
  const int wave = tid >> 6;         // 0..7
  const int wm = wave >> 2;          // 0..1 : 64-row half
  const int wn = wave & 3;           // 0..3 : 112-col quarter
  const int m  = lane & 15;
  const int g  = lane >> 4;

  const size_t swb = (size_t)(((lane & 7) ^ (lane >> 3)) * 16);
  const int bc0 = (wave < 4) ? wave * 4 : 16 + (wave - 4) * 3;
  const int nbc = (wave < 4) ? 4 : 3;
  const char* wpc = (const char*)Wp;

#pragma unroll 1
  for (int tile = blockIdx.x; tile < NTILE; tile += NGRID) {
    const int rb = tile * 128;

    f32x4 acc[4][7];
#pragma unroll
    for (int i = 0; i < 4; ++i)
#pragma unroll
      for (int j = 0; j < 7; ++j) acc[i][j] = (f32x4){0.f, 0.f, 0.f, 0.f};

    int gr0 = rb + wave * 16 + (lane >> 3);     if (gr0 > NROWS - 1) gr0 = NROWS - 1;
    int gr1 = rb + wave * 16 + 8 + (lane >> 3); if (gr1 > NROWS - 1) gr1 = NROWS - 1;
    const char* asrc0 = (const char*)X + (size_t)gr0 * 2048 + swb;
    const char* asrc1 = (const char*)X + (size_t)gr1 * 2048 + swb;

#define STAGE(T, BUF)                                                          \
    do {                                                                       \
      char* ad = Abase0 + (BUF) * 16384 + wave * 2048 + lane * 16;             \
      gload_lds16(asrc0 + (size_t)(T) * 128, ad);                              \
      gload_lds16(asrc1 + (size_t)(T) * 128, ad + 1024);                       \
      const char* bsrc = wpc + (size_t)(T) * 28672;                            \
      for (int q = 0; q < nbc; ++q)                                            \
        gload_lds16(bsrc + (bc0 + q) * 1024 + lane * 16,                       \
                    Bbase0 + (BUF) * 28672 + (bc0 + q) * 1024);                \
    } while (0)

    STAGE(0, 0);
    STAGE(1, 1);

#pragma unroll
    for (int t = 0; t < 16; ++t) {
      const int cur = t % 3;
      if (t < 15) {
        if (wave < 4) asm volatile("s_waitcnt vmcnt(6)\n\ts_barrier" ::: "memory");
        else          asm volatile("s_waitcnt vmcnt(5)\n\ts_barrier" ::: "memory");
      } else {
        asm volatile("s_waitcnt vmcnt(0)\n\ts_barrier" ::: "memory");
      }
      if (t + 2 < 16) STAGE(t + 2, (t + 2) % 3);

      const int sw = (m & 7) * 16;
      const char* abuf = Abase0 + cur * 16384;
      bf16x8 af[4];
#pragma unroll
      for (int mf = 0; mf < 4; ++mf) {
        const char* rowp = abuf + (wm * 64 + mf * 16 + m) * 128;
        f32x4 alo = *(const f32x4*)(rowp + ((16 * g) ^ sw));
        f32x4 ahi = *(const f32x4*)(rowp + ((64 + 16 * g) ^ sw));
        af[mf] = (bf16x8){(bf16)alo.x, (bf16)alo.y, (bf16)alo.z, (bf16)alo.w,
                          (bf16)ahi.x, (bf16)ahi.y, (bf16)ahi.z, (bf16)ahi.w};
      }

      const bf16* Bc = (const bf16*)(Bbase0 + cur * 28672);
      __builtin_amdgcn_s_setprio(1);
#pragma unroll
      for (int nf = 0; nf < 7; ++nf) {
        const int n = wn * 112 + nf * 16 + m;
        bf16x8 bfr = *(const bf16x8*)(Bc + (g * 448 + n) * 8);
#pragma unroll
        for (int mf = 0; mf < 4; ++mf)
          acc[mf][nf] = __builtin_amdgcn_mfma_f32_16x16x32_bf16(af[mf], bfr, acc[mf][nf], 0, 0, 0);
      }
      __builtin_amdgcn_s_setprio(0);
    }
#undef STAGE
    __syncthreads();   // all ds_reads done before pool reuse

    // ---- epilogue E1 ----
    bf16* ldsVZ = (bf16*)pool;              // [224][136] bf16 = 60928 B
    float* sp   = (float*)(pool + 61440);   // [8][112] f32
    float csum[7];
#pragma unroll
    for (int nf = 0; nf < 7; ++nf) csum[nf] = 0.f;

#pragma unroll
    for (int mf = 0; mf < 4; ++mf) {
#pragma unroll
      for (int nf = 0; nf < 7; ++nf) {
        const int c = wn * 112 + nf * 16 + m;
        const float bv = (c < NC) ? bias[c] : 0.f;
        const int rl0 = wm * 64 + mf * 16 + 4 * g;
        bf16 vz[4];
#pragma unroll
        for (int r = 0; r < 4; ++r) {
          const int row = rb + rl0 + r;
          float v = fmaxf(acc[mf][nf][r] + bv, 0.f);
          const float v2 = (row < NROWS) ? v : 0.f;
          if (row < NROWS) {
            if (c < 100) U[(size_t)row * 128 + c] = (bf16)v;
            if (c >= 300 && c < NC) out[(size_t)row * 200 + 100 + (c - 300)] = v;
          }
          vz[r] = (bf16)v2;
          if (c < 200) csum[nf] += v2;
        }
        if (c >= 100 && c < 300) {
          const int vr = (c < 200) ? (c - 100) : (112 + (c - 200));
          *(bf16x4*)&ldsVZ[(size_t)vr * 136 + rl0] = (bf16x4){vz[0], vz[1], vz[2], vz[3]};
        }
      }
    }
    for (int i = tid; i < 3264; i += 512) {
      const int q = i / 136, off = i % 136;
      const int lrow = (q < 12) ? (100 + q) : (200 + q);
      ldsVZ[lrow * 136 + off] = (bf16)0.f;
    }
#pragma unroll
    for (int nf = 0; nf < 7; ++nf) {
      float s = csum[nf];
      s += __shfl_xor(s, 16, 64);
      s += __shfl_xor(s, 32, 64);
      if (lane < 16) sp[wave * 112 + nf * 16 + lane] = s;
    }
    __syncthreads();

    // ---- epilogue E2: per-tile VtZ partial (112x112, K=128) + atomics ----
    if (wave < 7) {
      f32x4 acc2[7];
#pragma unroll
      for (int j = 0; j < 7; ++j) acc2[j] = (f32x4){0.f, 0.f, 0.f, 0.f};
      const bf16* vA = ldsVZ + (size_t)(wave * 16 + m) * 136;
#pragma unroll
      for (int kc = 0; kc < 4; ++kc) {
        bf16x4 a0 = *(const bf16x4*)(vA + kc * 32 + 4 * g);
        bf16x4 a1 = *(const bf16x4*)(vA + kc * 32 + 16 + 4 * g);
        bf16x8 af_ = {a0[0], a0[1], a0[2], a0[3], a1[0], a1[1], a1[2], a1[3]};
#pragma unroll
        for (int fj = 0; fj < 7; ++fj) {
          const bf16* vB = ldsVZ + (size_t)(112 + fj * 16 + m) * 136 + kc * 32;
          bf16x4 b0 = *(const bf16x4*)(vB + 4 * g);
          bf16x4 b1 = *(const bf16x4*)(vB + 16 + 4 * g);
          bf16x8 bf_ = {b0[0], b0[1], b0[2], b0[3], b1[0], b1[1], b1[2], b1[3]};
          acc2[fj] = __builtin_amdgcn_mfma_f32_16x16x32_bf16(af_, bf_, acc2[fj], 0, 0, 0);
        }
      }
      float* pb = part + (size_t)(tile % 98) * 12544;
#pragma unroll
      for (int fj = 0; fj < 7; ++fj)
#pragma unroll
        for (int r = 0; r < 4; ++r)
          atomicAdd(&pb[(wave * 16 + 4 * g + r) * 112 + fj * 16 + m], acc2[fj][r]);
    }
    if (tid < 200) {
      const int wnc = tid / 112, cc = tid % 112;
      sumP[(size_t)tile * 200 + tid] =
          sp[wnc * 112 + cc] + sp[(wnc + 4) * 112 + cc];
    }
    __syncthreads();   // E2 reads done before next tile stages into pool
  }
}

// ---- k4a0: reduce per-tile sums -> sumU/sumV ----
__global__ void k4a0_redsum(const float* __restrict__ sumP,
                            float* __restrict__ sumU, float* __restrict__ sumV) {
  __shared__ float red[4];
  const int c = blockIdx.x;          // 0..199
  const int tid = threadIdx.x;       // 256
  float s = 0.f;
  for (int b = tid; b < NTILE; b += 256) s += sumP[(size_t)b * 200 + c];
#pragma unroll
  for (int off = 1; off < 64; off <<= 1) s += __shfl_xor(s, off, 64);
  if ((tid & 63) == 0) red[tid >> 6] = s;
  __syncthreads();
  if (tid == 0) {
    float t = red[0] + red[1] + red[2] + red[3];
    if (c < 100) sumU[c] = t; else sumV[c - 100] = t;
  }
}

// ---- k4a: Dscale ----
__global__ void k4a_norm(const float* __restrict__ sumU, const float* __restrict__ sumV,
                         float* __restrict__ dsc) {
  const int l = threadIdx.x;  // 64
  float v = 0.f;
  if (l < 50) v = sumU[l] * sumV[l] + sumU[l + 50] * sumV[l + 50];
#pragma unroll
  for (int off = 32; off > 0; off >>= 1) v += __shfl_down(v, off, 64);
  if (l == 0) dsc[0] = 1.f / (v * (1.f / (float)NROWS) + 1e-6f);
}

// ---- k4b: reduce 98 f32 partials, scale, store transposed bf16 [j][128] ----
__global__ void k4b_final(const float* __restrict__ part, const float* __restrict__ dsc,
                          bf16* __restrict__ vtzt) {
  const int idx = blockIdx.x * 256 + threadIdx.x;   // 49 blocks
  if (idx < 1792) vtzt[(idx >> 4) * 128 + 112 + (idx & 15)] = (bf16)0.f;
  if (idx >= 12544) return;
  const int i = idx / 112;
  const int j = idx % 112;
  float s = 0.f;
#pragma unroll 7
  for (int bb = 0; bb < 98; ++bb) s += part[(size_t)bb * 12544 + idx];
  vtzt[j * 128 + i] = (bf16)(s * dsc[0]);
}

// ---- k5: res = U @ VtZS -> out[:, 0:100] ----
__global__ __launch_bounds__(256) void k5_res(
    const bf16* __restrict__ U, const bf16* __restrict__ vtzt,
    float* __restrict__ out) {
  const int tid = threadIdx.x;
  const int lane = tid & 63;
  const int wave = tid >> 6;
  const int m = lane & 15, g = lane >> 4;
  const int rb = blockIdx.x * 128 + wave * 32;

  f32x4 acc[2][7];
#pragma unroll
  for (int i = 0; i < 2; ++i)
#pragma unroll
    for (int j = 0; j < 7; ++j) acc[i][j] = (f32x4){0.f, 0.f, 0.f, 0.f};

  int r0 = rb + m;      if (r0 > NROWS - 1) r0 = NROWS - 1;
  int r1 = rb + 16 + m; if (r1 > NROWS - 1) r1 = NROWS - 1;
  const bf16* u0 = U + (size_t)r0 * 128 + 4 * g;
  const bf16* u1 = U + (size_t)r1 * 128 + 4 * g;
  const bf16* vb = vtzt + 4 * g;

#pragma unroll
  for (int ks = 0; ks < 4; ++ks) {
    bf16x4 A00 = *(const bf16x4*)(u0 + ks * 32);
    bf16x4 A01 = *(const bf16x4*)(u0 + ks * 32 + 16);
    bf16x4 A10 = *(const bf16x4*)(u1 + ks * 32);
    bf16x4 A11 = *(const bf16x4*)(u1 + ks * 32 + 16);
    bf16x8 af0 = {A00[0], A00[1], A00[2], A00[3], A01[0], A01[1], A01[2], A01[3]};
    bf16x8 af1 = {A10[0], A10[1], A10[2], A10[3], A11[0], A11[1], A11[2], A11[3]};
#pragma unroll
    for (int nf = 0; nf < 7; ++nf) {
      const int n = nf * 16 + m;
      bf16x4 B0 = *(const bf16x4*)(vb + n * 128 + ks * 32);
      bf16x4 B1 = *(const bf16x4*)(vb + n * 128 + ks * 32 + 16);
      bf16x8 bfr = {B0[0], B0[1], B0[2], B0[3], B1[0], B1[1], B1[2], B1[3]};
      acc[0][nf] = __builtin_amdgcn_mfma_f32_16x16x32_bf16(af0, bfr, acc[0][nf], 0, 0, 0);
      acc[1][nf] = __builtin_amdgcn_mfma_f32_16x16x32_bf16(af1, bfr, acc[1][nf], 0, 0, 0);
    }
  }
#pragma unroll
  for (int mf = 0; mf < 2; ++mf)
#pragma unroll
    for (int nf = 0; nf < 7; ++nf)
#pragma unroll
      for (int r = 0; r < 4; ++r) {
        const int row = rb + mf * 16 + 4 * g + r;
        const int c = nf * 16 + m;
        if (row < NROWS && c < 100)
          out[(size_t)row * 200 + c] = acc[mf][nf][r];
      }
}

extern "C" void kernel_launch(void* const* d_in, const int* in_sizes, int n_in,
                              void* d_out, int out_size, void* d_ws, size_t ws_size,
                              hipStream_t stream) {
  const float* X = (const float*)d_in[0];
  const float* W = (const float*)d_in[1];
  const float* b = (const float*)d_in[2];
  float* out = (float*)d_out;
  char* ws = (char*)d_ws;
  if (ws_size < WS_NEED) return;

  bf16* wp     = (bf16*)(ws + WS_WP);
  float* sumU  = (float*)(ws + WS_SUMU);
  float* sumV  = (float*)(ws + WS_SUMV);
  float* dsc   = (float*)(ws + WS_DSC);
  bf16* vtzt   = (bf16*)(ws + WS_VTZT);
  bf16* U      = (bf16*)(ws + WS_U);
  float* part  = (float*)(ws + WS_PART);
  float* sumP  = (float*)(ws + WS_SUMP);

  k1_prep<<<896, 256, 0, stream>>>(W, wp, sumU);
  hipMemsetAsync(part, 0, 98u * 12544u * 4u, stream);
  k2_main<<<NGRID, 512, 0, stream>>>(X, wp, b, out, U, part, sumP);
  k4a0_redsum<<<200, 256, 0, stream>>>(sumP, sumU, sumV);
  k4a_norm<<<1, 64, 0, stream>>>(sumU, sumV, dsc);
  k4b_final<<<49, 256, 0, stream>>>(part, dsc, vtzt);
  k5_res<<<782, 256, 0, stream>>>(U, vtzt, out);
}

// Round 19
// 173.791 us; speedup vs baseline: 2.0140x; 1.3243x over previous
//
#include <hip/hip_runtime.h>
#include <cstdint>

typedef __bf16 bf16;
typedef __attribute__((ext_vector_type(8))) __bf16 bf16x8;
typedef __attribute__((ext_vector_type(4))) __bf16 bf16x4;
typedef __attribute__((ext_vector_type(4))) float f32x4;

#define NROWS 100000
#define DIM   512
#define NC    400
#define NTILE 695          // ceil(100000/144), 3 dispatch rounds at 1 blk/CU

// ---- workspace layout (bytes) ----
#define WS_WP    0u          // packed W bf16: 458752 B
#define WS_SUMU  458752u
#define WS_SUMV  459152u
#define WS_DSC   459552u
#define WS_VTZT  459776u     // [112][128] bf16
#define WS_U     524288u     // [100000][128] bf16
#define WS_PART  66124288u   // 98 x 12544 f32
#define WS_SUMP  71041536u   // [695][200] f32 = 556000 B
#define WS_NEED  72291936u

__device__ __forceinline__ void gload_lds16(const void* g, void* l) {
  __builtin_amdgcn_global_load_lds(
      (const __attribute__((address_space(1))) uint32_t*)g,
      (__attribute__((address_space(3))) uint32_t*)l,
      16, 0, 0);
}

// ---- k1: pack W -> [t][g][448 col][8 e] bf16 (28672 B per tile); zero sums ----
__global__ void k1_prep(const float* __restrict__ W, bf16* __restrict__ wp,
                        float* __restrict__ sums) {
  const int idx = blockIdx.x * 256 + threadIdx.x;
  if (idx < 200) sums[idx] = 0.f;
  if (idx >= 16 * 4 * 448 * 8) return;
  const int e = idx & 7;
  int r = idx >> 3;
  const int col = r % 448; r /= 448;
  const int g = r & 3;
  const int t = r >> 2;
  const int k = t * 32 + 4 * g + ((e < 4) ? e : (12 + e));
  wp[idx] = (bf16)((col < NC) ? W[col * DIM + k] : 0.f);
}

// ---- k2: relu(X@Wt+b) + fused per-tile VtZ partial.
// BM=144 x BN=448, BK=32, 768 threads / 12 waves (3 row-groups x 4 col-
// quarters; wave = 48r x 112c, acc[3][7]). R16 schedule: 3-buf A+B, ONE
// wait+barrier per step, STAGE(t+2) after barrier, counted vmcnt spans
// barriers, setprio. FLAT (no tile loop -> no spill). 695 blocks = 3 rounds.
__global__ __launch_bounds__(768, 3) void k2_main(
    const float* __restrict__ X, const bf16* __restrict__ Wp,
    const float* __restrict__ bias, float* __restrict__ out,
    bf16* __restrict__ U, float* __restrict__ part, float* __restrict__ sumP) {
  __shared__ __align__(16) char pool[141312];  // A: 3x18KB @0 ; B: 3x28KB @55296
  char* Abase0 = pool;
  char* Bbase0 = pool + 55296;

  const int tid  = threadIdx.x;
  const int lane = tid & 63;
  const int wave = tid >> 6;        // 0..11
  const int wm = wave >> 2;         // 0..2 : 48-row group
  const int wn = wave & 3;          // 0..3 : 112-col quarter
  const int m  = lane & 15;
  const int g  = lane >> 4;
  const int rb = blockIdx.x * 144;

  f32x4 acc[3][7];
#pragma unroll
  for (int i = 0; i < 3; ++i)
#pragma unroll
    for (int j = 0; j < 7; ++j) acc[i][j] = (f32x4){0.f, 0.f, 0.f, 0.f};

  // A staging: 18 chunks of 8 rows x 128B. waves 0-5 own 2 chunks, 6-11 own 1.
  const int na  = (wave < 6) ? 2 : 1;
  const int ca0 = (wave < 6) ? wave * 2 : 12 + (wave - 6);
  const size_t swb = (size_t)(((lane & 7) ^ (lane >> 3)) * 16);
  int gr0 = rb + ca0 * 8 + (lane >> 3);       if (gr0 > NROWS - 1) gr0 = NROWS - 1;
  int gr1 = rb + (ca0 + 1) * 8 + (lane >> 3); if (gr1 > NROWS - 1) gr1 = NROWS - 1;
  const char* asrc0 = (const char*)X + (size_t)gr0 * 2048 + swb;
  const char* asrc1 = (const char*)X + (size_t)gr1 * 2048 + swb;
  // B staging: 28 chunks of 1024B. waves 0-3 own 3, waves 4-11 own 2.
  const int nbc = (wave < 4) ? 3 : 2;
  const int bc0 = (wave < 4) ? wave * 3 : 12 + (wave - 4) * 2;
  const char* wpc = (const char*)Wp;

#define STAGE(T, BUF)                                                          \
  do {                                                                         \
    char* ad = Abase0 + (BUF) * 18432 + ca0 * 1024 + lane * 16;                \
    gload_lds16(asrc0 + (size_t)(T) * 128, ad);                                \
    if (na == 2) gload_lds16(asrc1 + (size_t)(T) * 128, ad + 1024);            \
    const char* bsrc = wpc + (size_t)(T) * 28672;                              \
    for (int q = 0; q < nbc; ++q)                                              \
      gload_lds16(bsrc + (bc0 + q) * 1024 + lane * 16,                         \
                  Bbase0 + (BUF) * 28672 + (bc0 + q) * 1024);                  \
  } while (0)

  // prologue: tiles 0 and 1 in flight
  STAGE(0, 0);
  STAGE(1, 1);

#pragma unroll
  for (int t = 0; t < 16; ++t) {
    const int cur = t % 3;
    // drain stage(t); leave stage(t+1) (na+nbc per wave class); ONE barrier
    if (t < 15) {
      if (wave < 4)      asm volatile("s_waitcnt vmcnt(5)\n\ts_barrier" ::: "memory");
      else if (wave < 6) asm volatile("s_waitcnt vmcnt(4)\n\ts_barrier" ::: "memory");
      else               asm volatile("s_waitcnt vmcnt(3)\n\ts_barrier" ::: "memory");
    } else {
      asm volatile("s_waitcnt vmcnt(0)\n\ts_barrier" ::: "memory");
    }
    // stage t+2 into buf (t+2)%3 — not read until step t+2, no trailing barrier
    if (t + 2 < 16) STAGE(t + 2, (t + 2) % 3);

    // A fragments (swizzled read, f32 -> bf16), 3 m-frags
    const int sw = (m & 7) * 16;
    const char* abuf = Abase0 + cur * 18432;
    bf16x8 af[3];
#pragma unroll
    for (int mf = 0; mf < 3; ++mf) {
      const char* rowp = abuf + (wm * 48 + mf * 16 + m) * 128;
      f32x4 alo = *(const f32x4*)(rowp + ((16 * g) ^ sw));
      f32x4 ahi = *(const f32x4*)(rowp + ((64 + 16 * g) ^ sw));
      af[mf] = (bf16x8){(bf16)alo.x, (bf16)alo.y, (bf16)alo.z, (bf16)alo.w,
                        (bf16)ahi.x, (bf16)ahi.y, (bf16)ahi.z, (bf16)ahi.w};
    }

    const bf16* Bc = (const bf16*)(Bbase0 + cur * 28672);
    __builtin_amdgcn_s_setprio(1);
#pragma unroll
    for (int nf = 0; nf < 7; ++nf) {
      const int n = wn * 112 + nf * 16 + m;
      bf16x8 bfr = *(const bf16x8*)(Bc + (g * 448 + n) * 8);
#pragma unroll
      for (int mf = 0; mf < 3; ++mf)
        acc[mf][nf] = __builtin_amdgcn_mfma_f32_16x16x32_bf16(af[mf], bfr, acc[mf][nf], 0, 0, 0);
    }
    __builtin_amdgcn_s_setprio(0);
  }
#undef STAGE
  __syncthreads();   // all ds_reads done before pool reuse

  // ---- epilogue E1: bias+relu, U/T stores, V/Z -> LDS transposed, col sums ----
  // ldsVZ [224 rows][168 cols] bf16 = 75264 B (E2 reads K=160, cols 144+ zeroed)
  bf16* ldsVZ = (bf16*)pool;
  float* sp   = (float*)(pool + 75264);    // [12][112] f32 = 5376 B
  float csum[7];
#pragma unroll
  for (int nf = 0; nf < 7; ++nf) csum[nf] = 0.f;

#pragma unroll
  for (int mf = 0; mf < 3; ++mf) {
#pragma unroll
    for (int nf = 0; nf < 7; ++nf) {
      const int c = wn * 112 + nf * 16 + m;
      const float bv = (c < NC) ? bias[c] : 0.f;
      const int rl0 = wm * 48 + mf * 16 + 4 * g;   // 0..143
      bf16 vz[4];
#pragma unroll
      for (int r = 0; r < 4; ++r) {
        const int row = rb + rl0 + r;
        float v = fmaxf(acc[mf][nf][r] + bv, 0.f);
        const float v2 = (row < NROWS) ? v : 0.f;
        if (row < NROWS) {
          if (c < 100) U[(size_t)row * 128 + c] = (bf16)v;
          if (c >= 300 && c < NC) out[(size_t)row * 200 + 100 + (c - 300)] = v;
        }
        vz[r] = (bf16)v2;
        if (c < 200) csum[nf] += v2;
      }
      if (c >= 100 && c < 300) {
        const int vr = (c < 200) ? (c - 100) : (112 + (c - 200));
        *(bf16x4*)&ldsVZ[(size_t)vr * 168 + rl0] = (bf16x4){vz[0], vz[1], vz[2], vz[3]};
      }
    }
  }
  // zero: all 224 rows cols 144..167 (5376) + pad rows (V100-111,Z212-223) cols 0..143 (3456)
  for (int i = tid; i < 8832; i += 768) {
    int rr, cc;
    if (i < 5376) { rr = i / 24; cc = 144 + (i % 24); }
    else { const int j = i - 5376; const int q = j / 144; cc = j % 144;
           rr = (q < 12) ? (100 + q) : (200 + q); }
    ldsVZ[(size_t)rr * 168 + cc] = (bf16)0.f;
  }
#pragma unroll
  for (int nf = 0; nf < 7; ++nf) {
    float s = csum[nf];
    s += __shfl_xor(s, 16, 64);
    s += __shfl_xor(s, 32, 64);
    if (lane < 16) sp[wave * 112 + nf * 16 + lane] = s;
  }
  __syncthreads();

  // ---- epilogue E2: per-tile VtZ partial (112x112, K=160 padded) + atomics ----
  if (wave < 7) {
    f32x4 acc2[7];
#pragma unroll
    for (int j = 0; j < 7; ++j) acc2[j] = (f32x4){0.f, 0.f, 0.f, 0.f};
    const bf16* vA = ldsVZ + (size_t)(wave * 16 + m) * 168;
#pragma unroll
    for (int kc = 0; kc < 5; ++kc) {
      bf16x4 a0 = *(const bf16x4*)(vA + kc * 32 + 4 * g);
      bf16x4 a1 = *(const bf16x4*)(vA + kc * 32 + 16 + 4 * g);
      bf16x8 af_ = {a0[0], a0[1], a0[2], a0[3], a1[0], a1[1], a1[2], a1[3]};
#pragma unroll
      for (int fj = 0; fj < 7; ++fj) {
        const bf16* vB = ldsVZ + (size_t)(112 + fj * 16 + m) * 168 + kc * 32;
        bf16x4 b0 = *(const bf16x4*)(vB + 4 * g);
        bf16x4 b1 = *(const bf16x4*)(vB + 16 + 4 * g);
        bf16x8 bf_ = {b0[0], b0[1], b0[2], b0[3], b1[0], b1[1], b1[2], b1[3]};
        acc2[fj] = __builtin_amdgcn_mfma_f32_16x16x32_bf16(af_, bf_, acc2[fj], 0, 0, 0);
      }
    }
    float* pb = part + (size_t)(blockIdx.x % 98) * 12544;
#pragma unroll
    for (int fj = 0; fj < 7; ++fj)
#pragma unroll
      for (int r = 0; r < 4; ++r)
        atomicAdd(&pb[(wave * 16 + 4 * g + r) * 112 + fj * 16 + m], acc2[fj][r]);
  }
  if (tid < 200) {
    const int wq = tid / 112, cc = tid % 112;   // col quarter (0 or 1) + offset
    sumP[(size_t)blockIdx.x * 200 + tid] =
        sp[(0 * 4 + wq) * 112 + cc] + sp[(1 * 4 + wq) * 112 + cc] +
        sp[(2 * 4 + wq) * 112 + cc];
  }
}

// ---- k4a0: reduce per-tile sums -> sumU/sumV ----
__global__ void k4a0_redsum(const float* __restrict__ sumP,
                            float* __restrict__ sumU, float* __restrict__ sumV) {
  __shared__ float red[4];
  const int c = blockIdx.x;          // 0..199
  const int tid = threadIdx.x;       // 256
  float s = 0.f;
  for (int b = tid; b < NTILE; b += 256) s += sumP[(size_t)b * 200 + c];
#pragma unroll
  for (int off = 1; off < 64; off <<= 1) s += __shfl_xor(s, off, 64);
  if ((tid & 63) == 0) red[tid >> 6] = s;
  __syncthreads();
  if (tid == 0) {
    float t = red[0] + red[1] + red[2] + red[3];
    if (c < 100) sumU[c] = t; else sumV[c - 100] = t;
  }
}

// ---- k4a: Dscale ----
__global__ void k4a_norm(const float* __restrict__ sumU, const float* __restrict__ sumV,
                         float* __restrict__ dsc) {
  const int l = threadIdx.x;  // 64
  float v = 0.f;
  if (l < 50) v = sumU[l] * sumV[l] + sumU[l + 50] * sumV[l + 50];
#pragma unroll
  for (int off = 32; off > 0; off >>= 1) v += __shfl_down(v, off, 64);
  if (l == 0) dsc[0] = 1.f / (v * (1.f / (float)NROWS) + 1e-6f);
}

// ---- k4b: reduce 98 f32 partials, scale, store transposed bf16 [j][128] ----
__global__ void k4b_final(const float* __restrict__ part, const float* __restrict__ dsc,
                          bf16* __restrict__ vtzt) {
  const int idx = blockIdx.x * 256 + threadIdx.x;   // 49 blocks
  if (idx < 1792) vtzt[(idx >> 4) * 128 + 112 + (idx & 15)] = (bf16)0.f;
  if (idx >= 12544) return;
  const int i = idx / 112;
  const int j = idx % 112;
  float s = 0.f;
#pragma unroll 7
  for (int bb = 0; bb < 98; ++bb) s += part[(size_t)bb * 12544 + idx];
  vtzt[j * 128 + i] = (bf16)(s * dsc[0]);
}

// ---- k5: res = U @ VtZS -> out[:, 0:100] ----
__global__ __launch_bounds__(256) void k5_res(
    const bf16* __restrict__ U, const bf16* __restrict__ vtzt,
    float* __restrict__ out) {
  const int tid = threadIdx.x;
  const int lane = tid & 63;
  const int wave = tid >> 6;
  const int m = lane & 15, g = lane >> 4;
  const int rb = blockIdx.x * 128 + wave * 32;

  f32x4 acc[2][7];
#pragma unroll
  for (int i = 0; i < 2; ++i)
#pragma unroll
    for (int j = 0; j < 7; ++j) acc[i][j] = (f32x4){0.f, 0.f, 0.f, 0.f};

  int r0 = rb + m;      if (r0 > NROWS - 1) r0 = NROWS - 1;
  int r1 = rb + 16 + m; if (r1 > NROWS - 1) r1 = NROWS - 1;
  const bf16* u0 = U + (size_t)r0 * 128 + 4 * g;
  const bf16* u1 = U + (size_t)r1 * 128 + 4 * g;
  const bf16* vb = vtzt + 4 * g;

#pragma unroll
  for (int ks = 0; ks < 4; ++ks) {
    bf16x4 A00 = *(const bf16x4*)(u0 + ks * 32);
    bf16x4 A01 = *(const bf16x4*)(u0 + ks * 32 + 16);
    bf16x4 A10 = *(const bf16x4*)(u1 + ks * 32);
    bf16x4 A11 = *(const bf16x4*)(u1 + ks * 32 + 16);
    bf16x8 af0 = {A00[0], A00[1], A00[2], A00[3], A01[0], A01[1], A01[2], A01[3]};
    bf16x8 af1 = {A10[0], A10[1], A10[2], A10[3], A11[0], A11[1], A11[2], A11[3]};
#pragma unroll
    for (int nf = 0; nf < 7; ++nf) {
      const int n = nf * 16 + m;
      bf16x4 B0 = *(const bf16x4*)(vb + n * 128 + ks * 32);
      bf16x4 B1 = *(const bf16x4*)(vb + n * 128 + ks * 32 + 16);
      bf16x8 bfr = {B0[0], B0[1], B0[2], B0[3], B1[0], B1[1], B1[2], B1[3]};
      acc[0][nf] = __builtin_amdgcn_mfma_f32_16x16x32_bf16(af0, bfr, acc[0][nf], 0, 0, 0);
      acc[1][nf] = __builtin_amdgcn_mfma_f32_16x16x32_bf16(af1, bfr, acc[1][nf], 0, 0, 0);
    }
  }
#pragma unroll
  for (int mf = 0; mf < 2; ++mf)
#pragma unroll
    for (int nf = 0; nf < 7; ++nf)
#pragma unroll
      for (int r = 0; r < 4; ++r) {
        const int row = rb + mf * 16 + 4 * g + r;
        const int c = nf * 16 + m;
        if (row < NROWS && c < 100)
          out[(size_t)row * 200 + c] = acc[mf][nf][r];
      }
}

extern "C" void kernel_launch(void* const* d_in, const int* in_sizes, int n_in,
                              void* d_out, int out_size, void* d_ws, size_t ws_size,
                              hipStream_t stream) {
  const float* X = (const float*)d_in[0];
  const float* W = (const float*)d_in[1];
  const float* b = (const float*)d_in[2];
  float* out = (float*)d_out;
  char* ws = (char*)d_ws;
  if (ws_size < WS_NEED) return;

  bf16* wp     = (bf16*)(ws + WS_WP);
  float* sumU  = (float*)(ws + WS_SUMU);
  float* sumV  = (float*)(ws + WS_SUMV);
  float* dsc   = (float*)(ws + WS_DSC);
  bf16* vtzt   = (bf16*)(ws + WS_VTZT);
  bf16* U      = (bf16*)(ws + WS_U);
  float* part  = (float*)(ws + WS_PART);
  float* sumP  = (float*)(ws + WS_SUMP);

  k1_prep<<<896, 256, 0, stream>>>(W, wp, sumU);
  hipMemsetAsync(part, 0, 98u * 12544u * 4u, stream);
  k2_main<<<NTILE, 768, 0, stream>>>(X, wp, b, out, U, part, sumP);
  k4a0_redsum<<<200, 256, 0, stream>>>(sumP, sumU, sumV);
  k4a_norm<<<1, 64, 0, stream>>>(sumU, sumV, dsc);
  k4b_final<<<49, 256, 0, stream>>>(part, dsc, vtzt);
  k5_res<<<782, 256, 0, stream>>>(U, vtzt, out);
}